// Round 10
// baseline (655.930 us; speedup 1.0000x reference)
//
#include <hip/hip_runtime.h>
#include <hip/hip_bf16.h>
#include <hip/hip_fp16.h>
#include <cstdint>
#include <cstddef>

// B=64, D=512, T=1024, L=512
// prep:  xt[b][t][d] bf16 ; W1t[l][d] bf16 ; W2t[n=1536][k=1024] bf16 ; il bf16
// K1:    u = cos(xt @ rff_w + b)            (MFMA 128x128 BK=64 swizzled LDS)
// LN:    z = layernorm(u)                   (bf16, one wave per row)
// K2:    gates = act([z_t||z_prev] @ W2t^T) (MFMA 128x128 BK=64, dbuf
//                                            issue-early 2-phase pipeline)
// scan (segmented): k3a summaries -> k3b combine -> k3c emit + transpose
//
// LESSONS: (r4-r6) acc arrays are NOT SROA-promoted -> scratch RMW; use NAMED
// accumulators. (r8) XOR swizzle both-sides -> bank conflicts 2.5e7 -> 0.
// (r9 FAIL) loads in flight ACROSS raw s_barriers race (no IR memory fence;
// vmcnt orders only the issuing wave). Safe form: stage next tile at iteration
// TOP into the other buffer, vmcnt(0)+barrier once per tile -> no load ever
// crosses a barrier, overlap comes from issue-early.

typedef float f32x4 __attribute__((ext_vector_type(4)));
typedef short s16x8 __attribute__((ext_vector_type(8)));

__device__ __forceinline__ void gload_lds16(const void* g, void* l) {
  __builtin_amdgcn_global_load_lds(
      (const __attribute__((address_space(1))) void*)g,
      (__attribute__((address_space(3))) void*)l, 16, 0, 0);
}
__device__ __forceinline__ ushort f2bf(float f) {
  uint32_t u = __float_as_uint(f);
  return (ushort)((u + 0x7FFF + ((u >> 16) & 1)) >> 16);  // RNE
}
__device__ __forceinline__ float bf2f(ushort s) {
  return __uint_as_float(((uint32_t)s) << 16);
}
__device__ __forceinline__ ushort f2h(float f) {
  return __half_as_ushort(__float2half(f));
}
__device__ __forceinline__ float h2f(ushort s) {
  return __half2float(__ushort_as_half(s));
}

#define MF(d, a, b) d = __builtin_amdgcn_mfma_f32_16x16x32_bf16(a, b, d, 0, 0, 0);

// ------------------------------------------------ prep: W1 transpose (small)
__global__ __launch_bounds__(256) void transpose_cvt(
    const float* __restrict__ src, ushort* __restrict__ dst, int ld)
{
  __shared__ float tile[32][33];
  const int c0 = blockIdx.x * 32, r0 = blockIdx.y * 32;
  const int tx = threadIdx.x & 31, ty = threadIdx.x >> 5;
#pragma unroll
  for (int i = 0; i < 4; ++i)
    tile[ty + i * 8][tx] = src[(size_t)(r0 + ty + i * 8) * 512 + c0 + tx];
  __syncthreads();
#pragma unroll
  for (int i = 0; i < 4; ++i)
    dst[(size_t)(c0 + ty + i * 8) * ld + r0 + tx] = f2bf(tile[tx][ty + i * 8]);
}

// ------------------------------------------------ prep: 6 gate weights + il
__global__ __launch_bounds__(256) void transpose6(
    const float* __restrict__ s0, const float* __restrict__ s1,
    const float* __restrict__ s2, const float* __restrict__ s3,
    const float* __restrict__ s4, const float* __restrict__ s5,
    const float* __restrict__ il, ushort* __restrict__ W2t,
    ushort* __restrict__ ilb)
{
  const int z = blockIdx.z;
  if (z == 6) {
    if (blockIdx.x == 0 && blockIdx.y == 0) {
      ilb[threadIdx.x] = f2bf(il[threadIdx.x]);
      ilb[threadIdx.x + 256] = f2bf(il[threadIdx.x + 256]);
    }
    return;
  }
  const float* src = z == 0 ? s0 : z == 1 ? s1 : z == 2 ? s2
                   : z == 3 ? s3 : z == 4 ? s4 : s5;
  ushort* dst = W2t + (size_t)(z >> 1) * 512 * 1024 + (z & 1) * 512;
  __shared__ float tile[32][33];
  const int c0 = blockIdx.x * 32, r0 = blockIdx.y * 32;
  const int tx = threadIdx.x & 31, ty = threadIdx.x >> 5;
#pragma unroll
  for (int i = 0; i < 4; ++i)
    tile[ty + i * 8][tx] = src[(size_t)(r0 + ty + i * 8) * 512 + c0 + tx];
  __syncthreads();
#pragma unroll
  for (int i = 0; i < 4; ++i)
    dst[(size_t)(c0 + ty + i * 8) * 1024 + r0 + tx] = f2bf(tile[tx][ty + i * 8]);
}

// ------------------------------------------------ prep: x[b][d][t] -> xt[b][t][d]
__global__ __launch_bounds__(256) void transpose_x(
    const float* __restrict__ x, ushort* __restrict__ xt)
{
  __shared__ float tile[64][68];
  const int b = blockIdx.z;
  const int t0 = blockIdx.x * 64, d0 = blockIdx.y * 64;
  const float* src = x + ((size_t)b * 512 + d0) * 1024 + t0;
  const int lr_ = threadIdx.x >> 4, lc4 = (threadIdx.x & 15) * 4;
#pragma unroll
  for (int p = 0; p < 4; ++p) {
    const float4 v = *(const float4*)(src + (size_t)(lr_ + p * 16) * 1024 + lc4);
    *(float4*)&tile[lr_ + p * 16][lc4] = v;
  }
  __syncthreads();
  const int tt = threadIdx.x >> 2, dc = (threadIdx.x & 3) * 16;
  ushort* dst = xt + ((size_t)b * 1024 + t0 + tt) * 512 + d0 + dc;
  uint4 o1, o2;
  o1.x = (uint)f2bf(tile[dc + 0][tt]) | ((uint)f2bf(tile[dc + 1][tt]) << 16);
  o1.y = (uint)f2bf(tile[dc + 2][tt]) | ((uint)f2bf(tile[dc + 3][tt]) << 16);
  o1.z = (uint)f2bf(tile[dc + 4][tt]) | ((uint)f2bf(tile[dc + 5][tt]) << 16);
  o1.w = (uint)f2bf(tile[dc + 6][tt]) | ((uint)f2bf(tile[dc + 7][tt]) << 16);
  o2.x = (uint)f2bf(tile[dc + 8][tt]) | ((uint)f2bf(tile[dc + 9][tt]) << 16);
  o2.y = (uint)f2bf(tile[dc + 10][tt]) | ((uint)f2bf(tile[dc + 11][tt]) << 16);
  o2.z = (uint)f2bf(tile[dc + 12][tt]) | ((uint)f2bf(tile[dc + 13][tt]) << 16);
  o2.w = (uint)f2bf(tile[dc + 14][tt]) | ((uint)f2bf(tile[dc + 15][tt]) << 16);
  *(uint4*)(dst) = o1;
  *(uint4*)(dst + 8) = o2;
}

// ------------------------------------------------ K1 (r8-verified, unchanged)
__global__ __launch_bounds__(256, 2) void k1_mfma(
    const ushort* __restrict__ A, const ushort* __restrict__ Bt,
    const float* __restrict__ bias, ushort* __restrict__ U)
{
  __shared__ __align__(16) short As[128 * 64];
  __shared__ __align__(16) short Bs[128 * 64];
  const int tid = threadIdx.x;
  const int lane = tid & 63, wid = tid >> 6;
  const int orig = blockIdx.x;
  const int swz = (orig & 7) * 256 + (orig >> 3);
  const int n0 = (swz & 3) * 128, r0 = (swz >> 2) * 128;
  const int wr = wid >> 1, wc = wid & 1;
  const int fr = lane & 15, fq = lane >> 4;
  const int lr = lane >> 3;
  const int swz_el = ((lane & 7) ^ lr) * 8;

  const int RA = r0 + wid * 32 + lr;
  const ushort* pa0 = A + (size_t)(RA)      * 512 + swz_el;
  const ushort* pa1 = A + (size_t)(RA + 8)  * 512 + swz_el;
  const ushort* pa2 = A + (size_t)(RA + 16) * 512 + swz_el;
  const ushort* pa3 = A + (size_t)(RA + 24) * 512 + swz_el;
  const int RB = n0 + wid * 32 + lr;
  const ushort* pb0 = Bt + (size_t)(RB)      * 512 + swz_el;
  const ushort* pb1 = Bt + (size_t)(RB + 8)  * 512 + swz_el;
  const ushort* pb2 = Bt + (size_t)(RB + 16) * 512 + swz_el;
  const ushort* pb3 = Bt + (size_t)(RB + 24) * 512 + swz_el;
  char* dA = (char*)As + wid * 4096;
  char* dB = (char*)Bs + wid * 4096;

  const int so0 = fr * 64 + ((fq)     ^ (fr & 7)) * 8;
  const int so1 = fr * 64 + ((4 + fq) ^ (fr & 7)) * 8;

  f32x4 c00 = {0.f,0.f,0.f,0.f}, c01 = c00, c02 = c00, c03 = c00,
        c10 = c00, c11 = c00, c12 = c00, c13 = c00,
        c20 = c00, c21 = c00, c22 = c00, c23 = c00,
        c30 = c00, c31 = c00, c32 = c00, c33 = c00;

  for (int k0 = 0; k0 < 512; k0 += 64) {
    gload_lds16(pa0 + k0, dA);        gload_lds16(pa1 + k0, dA + 1024);
    gload_lds16(pa2 + k0, dA + 2048); gload_lds16(pa3 + k0, dA + 3072);
    gload_lds16(pb0 + k0, dB);        gload_lds16(pb1 + k0, dB + 1024);
    gload_lds16(pb2 + k0, dB + 2048); gload_lds16(pb3 + k0, dB + 3072);
    __syncthreads();
    const s16x8 a00 = *(const s16x8*)&As[wr * 4096 + 0 * 1024 + so0];
    const s16x8 a01 = *(const s16x8*)&As[wr * 4096 + 0 * 1024 + so1];
    const s16x8 a10 = *(const s16x8*)&As[wr * 4096 + 1 * 1024 + so0];
    const s16x8 a11 = *(const s16x8*)&As[wr * 4096 + 1 * 1024 + so1];
    const s16x8 a20 = *(const s16x8*)&As[wr * 4096 + 2 * 1024 + so0];
    const s16x8 a21 = *(const s16x8*)&As[wr * 4096 + 2 * 1024 + so1];
    const s16x8 a30 = *(const s16x8*)&As[wr * 4096 + 3 * 1024 + so0];
    const s16x8 a31 = *(const s16x8*)&As[wr * 4096 + 3 * 1024 + so1];
    const s16x8 b00 = *(const s16x8*)&Bs[wc * 4096 + 0 * 1024 + so0];
    const s16x8 b01 = *(const s16x8*)&Bs[wc * 4096 + 0 * 1024 + so1];
    const s16x8 b10 = *(const s16x8*)&Bs[wc * 4096 + 1 * 1024 + so0];
    const s16x8 b11 = *(const s16x8*)&Bs[wc * 4096 + 1 * 1024 + so1];
    const s16x8 b20 = *(const s16x8*)&Bs[wc * 4096 + 2 * 1024 + so0];
    const s16x8 b21 = *(const s16x8*)&Bs[wc * 4096 + 2 * 1024 + so1];
    const s16x8 b30 = *(const s16x8*)&Bs[wc * 4096 + 3 * 1024 + so0];
    const s16x8 b31 = *(const s16x8*)&Bs[wc * 4096 + 3 * 1024 + so1];
    MF(c00, a00, b00) MF(c01, a00, b10) MF(c02, a00, b20) MF(c03, a00, b30)
    MF(c10, a10, b00) MF(c11, a10, b10) MF(c12, a10, b20) MF(c13, a10, b30)
    MF(c20, a20, b00) MF(c21, a20, b10) MF(c22, a20, b20) MF(c23, a20, b30)
    MF(c30, a30, b00) MF(c31, a30, b10) MF(c32, a30, b20) MF(c33, a30, b30)
    MF(c00, a01, b01) MF(c01, a01, b11) MF(c02, a01, b21) MF(c03, a01, b31)
    MF(c10, a11, b01) MF(c11, a11, b11) MF(c12, a11, b21) MF(c13, a11, b31)
    MF(c20, a21, b01) MF(c21, a21, b11) MF(c22, a21, b21) MF(c23, a21, b31)
    MF(c30, a31, b01) MF(c31, a31, b11) MF(c32, a31, b21) MF(c33, a31, b31)
    __syncthreads();
  }

#define EPI1(cmn, m_, n_) { \
    const int col = n0 + wc * 64 + n_ * 16 + fr; \
    const float bv = bias[col]; \
    const int rbase = r0 + wr * 64 + m_ * 16 + fq * 4; \
    _Pragma("unroll") for (int j = 0; j < 4; ++j) \
      U[(size_t)(rbase + j) * 512 + col] = f2bf(cosf(cmn[j] + bv)); }
  EPI1(c00, 0, 0) EPI1(c01, 0, 1) EPI1(c02, 0, 2) EPI1(c03, 0, 3)
  EPI1(c10, 1, 0) EPI1(c11, 1, 1) EPI1(c12, 1, 2) EPI1(c13, 1, 3)
  EPI1(c20, 2, 0) EPI1(c21, 2, 1) EPI1(c22, 2, 2) EPI1(c23, 2, 3)
  EPI1(c30, 3, 0) EPI1(c31, 3, 1) EPI1(c32, 3, 2) EPI1(c33, 3, 3)
#undef EPI1
}

// ------------------------------------------------ LN: one wave per 512-row
__global__ __launch_bounds__(256) void ln_rows(
    const ushort* __restrict__ U, ushort* __restrict__ Z)
{
  const int row = blockIdx.x * 4 + (threadIdx.x >> 6);
  const int lane = threadIdx.x & 63;
  const size_t base = (size_t)row * 512 + lane * 8;
  const uint4 pk = *(const uint4*)(U + base);
  float v[8];
  v[0] = bf2f(pk.x & 0xffff); v[1] = bf2f(pk.x >> 16);
  v[2] = bf2f(pk.y & 0xffff); v[3] = bf2f(pk.y >> 16);
  v[4] = bf2f(pk.z & 0xffff); v[5] = bf2f(pk.z >> 16);
  v[6] = bf2f(pk.w & 0xffff); v[7] = bf2f(pk.w >> 16);
  float s = 0.f, s2 = 0.f;
#pragma unroll
  for (int j = 0; j < 8; ++j) { s += v[j]; s2 += v[j] * v[j]; }
#pragma unroll
  for (int m = 1; m < 64; m <<= 1) { s += __shfl_xor(s, m); s2 += __shfl_xor(s2, m); }
  const float mean = s * (1.f / 512.f);
  const float var = s2 * (1.f / 512.f) - mean * mean;
  const float inv = rsqrtf(var + 1e-5f);
  uint4 o;
  o.x = (uint)f2bf((v[0] - mean) * inv) | ((uint)f2bf((v[1] - mean) * inv) << 16);
  o.y = (uint)f2bf((v[2] - mean) * inv) | ((uint)f2bf((v[3] - mean) * inv) << 16);
  o.z = (uint)f2bf((v[4] - mean) * inv) | ((uint)f2bf((v[5] - mean) * inv) << 16);
  o.w = (uint)f2bf((v[6] - mean) * inv) | ((uint)f2bf((v[7] - mean) * inv) << 16);
  *(uint4*)(Z + base) = o;
}

// ------------------------------------------------ K2: 128x128 BK=64, dbuf,
// issue-early 2-phase: stage tile kt+1 at iteration top into other buffer,
// vmcnt(0)+barrier once per tile. No load crosses a barrier (r9 lesson).
__global__ __launch_bounds__(256, 2) void k2_mfma(
    const ushort* __restrict__ Z, const ushort* __restrict__ Wt,
    const ushort* __restrict__ IL,
    const float* __restrict__ b0v, const float* __restrict__ b1v,
    const float* __restrict__ b2v,
    ushort* __restrict__ gates, int tc, int Tc, int nwg)
{
  __shared__ __align__(16) short As[2][128 * 64];   // 2 x 16 KB
  __shared__ __align__(16) short Bs[2][128 * 64];   // 2 x 16 KB
  const int tid = threadIdx.x;
  const int lane = tid & 63, wid = tid >> 6;
  const int cpx = nwg >> 3;
  const int orig = blockIdx.x;
  const int swz = (orig & 7) * cpx + (orig >> 3);
  const int bx = swz % 12, by = swz / 12;
  const int nb = Tc >> 7;
  const int b = by / nb, tb = by % nb;
  const int r0g = b * 1024 + tc + tb * 128;
  const int r0c = b * Tc + tb * 128;
  const int n0 = bx * 128;
  const int wr = wid >> 1, wc = wid & 1;
  const int fr = lane & 15, fq = lane >> 4;
  const int lr = lane >> 3;
  const int swz_el = ((lane & 7) ^ lr) * 8;

  const int R0 = r0g + wid * 32 + lr;
  const ushort* pa0 = Z + (size_t)(R0)      * 512 + swz_el;
  const ushort* pa1 = Z + (size_t)(R0 + 8)  * 512 + swz_el;
  const ushort* pa2 = Z + (size_t)(R0 + 16) * 512 + swz_el;
  const ushort* pa3 = Z + (size_t)(R0 + 24) * 512 + swz_el;
  const ushort* ph0 = ((((R0)      & 1023) == 0) ? IL : (Z + (size_t)(R0 - 1)  * 512)) + swz_el;
  const ushort* ph1 = ((((R0 + 8)  & 1023) == 0) ? IL : (Z + (size_t)(R0 + 7)  * 512)) + swz_el;
  const ushort* ph2 = ((((R0 + 16) & 1023) == 0) ? IL : (Z + (size_t)(R0 + 15) * 512)) + swz_el;
  const ushort* ph3 = ((((R0 + 24) & 1023) == 0) ? IL : (Z + (size_t)(R0 + 23) * 512)) + swz_el;
  const int RB = n0 + wid * 32 + lr;
  const ushort* pb0 = Wt + (size_t)(RB)      * 1024 + swz_el;
  const ushort* pb1 = Wt + (size_t)(RB + 8)  * 1024 + swz_el;
  const ushort* pb2 = Wt + (size_t)(RB + 16) * 1024 + swz_el;
  const ushort* pb3 = Wt + (size_t)(RB + 24) * 1024 + swz_el;

  // stage K-tile kt_ (8 gload_lds) into buffer BUF_
#define STG(kt_, BUF_) { \
    char* dA = (char*)As + (BUF_) * 16384 + wid * 4096; \
    char* dB = (char*)Bs + (BUF_) * 16384 + wid * 4096; \
    if ((kt_) < 8) { const int ko = (kt_) * 64; \
      gload_lds16(pa0 + ko, dA);        gload_lds16(pa1 + ko, dA + 1024); \
      gload_lds16(pa2 + ko, dA + 2048); gload_lds16(pa3 + ko, dA + 3072); \
    } else { const int ko = ((kt_) - 8) * 64; \
      gload_lds16(ph0 + ko, dA);        gload_lds16(ph1 + ko, dA + 1024); \
      gload_lds16(ph2 + ko, dA + 2048); gload_lds16(ph3 + ko, dA + 3072); } \
    { const int kb = (kt_) * 64; \
      gload_lds16(pb0 + kb, dB);        gload_lds16(pb1 + kb, dB + 1024); \
      gload_lds16(pb2 + kb, dB + 2048); gload_lds16(pb3 + kb, dB + 3072); } }

  f32x4 zz = {0.f,0.f,0.f,0.f};
  f32x4 c00=zz,c01=zz,c02=zz,c03=zz, c10=zz,c11=zz,c12=zz,c13=zz,
        c20=zz,c21=zz,c22=zz,c23=zz, c30=zz,c31=zz,c32=zz,c33=zz;
  s16x8 fa0, fa1, fa2, fa3, fb0, fb1, fb2, fb3;

#define RD(BUF_, KS_) { \
    const int so = fr * 64 + (((KS_) * 4 + fq) ^ (fr & 7)) * 8; \
    const short* A_ = &As[BUF_][0]; \
    const short* B_ = &Bs[BUF_][0]; \
    fa0 = *(const s16x8*)&A_[wr * 4096 + 0 * 1024 + so]; \
    fa1 = *(const s16x8*)&A_[wr * 4096 + 1 * 1024 + so]; \
    fa2 = *(const s16x8*)&A_[wr * 4096 + 2 * 1024 + so]; \
    fa3 = *(const s16x8*)&A_[wr * 4096 + 3 * 1024 + so]; \
    fb0 = *(const s16x8*)&B_[wc * 4096 + 0 * 1024 + so]; \
    fb1 = *(const s16x8*)&B_[wc * 4096 + 1 * 1024 + so]; \
    fb2 = *(const s16x8*)&B_[wc * 4096 + 2 * 1024 + so]; \
    fb3 = *(const s16x8*)&B_[wc * 4096 + 3 * 1024 + so]; }

#define MM \
    MF(c00,fa0,fb0) MF(c01,fa0,fb1) MF(c02,fa0,fb2) MF(c03,fa0,fb3) \
    MF(c10,fa1,fb0) MF(c11,fa1,fb1) MF(c12,fa1,fb2) MF(c13,fa1,fb3) \
    MF(c20,fa2,fb0) MF(c21,fa2,fb1) MF(c22,fa2,fb2) MF(c23,fa2,fb3) \
    MF(c30,fa3,fb0) MF(c31,fa3,fb1) MF(c32,fa3,fb2) MF(c33,fa3,fb3)

  STG(0, 0)
  asm volatile("s_waitcnt vmcnt(0)" ::: "memory");
  __builtin_amdgcn_s_barrier();
  __builtin_amdgcn_sched_barrier(0);
#pragma unroll
  for (int kt = 0; kt < 16; ++kt) {
    const int cur = kt & 1;
    if (kt < 15) { STG(kt + 1, cur ^ 1) }   // issue-early: flies under compute
    RD(cur, 0)
    __builtin_amdgcn_s_setprio(1);
    MM
    __builtin_amdgcn_s_setprio(0);
    RD(cur, 1)
    __builtin_amdgcn_s_setprio(1);
    MM
    __builtin_amdgcn_s_setprio(0);
    __builtin_amdgcn_sched_barrier(0);
    asm volatile("s_waitcnt vmcnt(0)" ::: "memory");  // drain own stage loads
    __builtin_amdgcn_s_barrier();                     // all waves: tile ready
    __builtin_amdgcn_sched_barrier(0);
  }
#undef MM
#undef RD
#undef STG

  const int sel = n0 >> 9;
  const float* bb = sel == 0 ? b0v : (sel == 1 ? b1v : b2v);
#define EPI(cmn, m_, n_) { \
    const int col = n0 + wc * 64 + n_ * 16 + fr; \
    const float bv = bb[col & 511]; \
    const int rbase = wr * 64 + m_ * 16 + fq * 4; \
    _Pragma("unroll") for (int j = 0; j < 4; ++j) { \
      const float uu = cmn[j] + bv; \
      const float vv = (sel < 2) ? (1.f / (1.f + __expf(-uu))) \
                                 : (2.f / (1.f + __expf(-2.f * uu)) - 1.f); \
      gates[(size_t)(r0c + rbase + j) * 1536 + col] = f2h(vv); } }
  EPI(c00, 0, 0) EPI(c01, 0, 1) EPI(c02, 0, 2) EPI(c03, 0, 3)
  EPI(c10, 1, 0) EPI(c11, 1, 1) EPI(c12, 1, 2) EPI(c13, 1, 3)
  EPI(c20, 2, 0) EPI(c21, 2, 1) EPI(c22, 2, 2) EPI(c23, 2, 3)
  EPI(c30, 3, 0) EPI(c31, 3, 1) EPI(c32, 3, 2) EPI(c33, 3, 3)
#undef EPI
}

// ------------------------------------------------ scan phase A
__global__ __launch_bounds__(256) void k3a_seg(
    const ushort* __restrict__ gates, float* __restrict__ Aseg,
    float* __restrict__ Bseg, int Tc)
{
  const int l = blockIdx.x * 256 + threadIdx.x;
  const int b = blockIdx.y, s = blockIdx.z;
  const int SEGc = Tc >> 6;
  const ushort* gb = gates + ((size_t)(b * Tc + s * 64)) * 1536 + l;
  float A = 1.f, c = 0.f;
#pragma unroll 8
  for (int j = 0; j < 64; ++j) {
    const float iv = h2f(gb[(size_t)j * 1536]);
    const float fv = h2f(gb[(size_t)j * 1536 + 512]);
    const float gv = h2f(gb[(size_t)j * 1536 + 1024]);
    A *= fv;
    c = fmaf(fv, c, iv * gv);
  }
  const size_t o = (size_t)(b * SEGc + s) * 512 + l;
  Aseg[o] = A;
  Bseg[o] = c;
}

// ------------------------------------------------ scan phase B
__global__ __launch_bounds__(512) void k3b_comb(
    const float* __restrict__ Aseg, const float* __restrict__ Bseg,
    const float* __restrict__ initc, float* __restrict__ cstart,
    float* __restrict__ cbuf, int tc, int Tc)
{
  const int b = blockIdx.x, l = threadIdx.x;
  const int SEGc = Tc >> 6;
  float c = (tc == 0) ? initc[l] : cbuf[b * 512 + l];
  for (int s = 0; s < SEGc; ++s) {
    const size_t o = (size_t)(b * SEGc + s) * 512 + l;
    cstart[o] = c;
    c = fmaf(Aseg[o], c, Bseg[o]);
  }
  cbuf[b * 512 + l] = c;
}

// ------------------------------------------------ scan phase C
__global__ __launch_bounds__(128) void k3c_emit(
    const ushort* __restrict__ gates, const ushort* __restrict__ Z,
    const float* __restrict__ cstart, float* __restrict__ out,
    int tc, int Tc)
{
  __shared__ float tile[128][65];
  const int tid = threadIdx.x;
  const int l0 = blockIdx.x * 128;
  const int b = blockIdx.y, s = blockIdx.z;
  const int SEGc = Tc >> 6;
  const int l = l0 + tid;

  float c = cstart[(size_t)(b * SEGc + s) * 512 + l];
  const ushort* gb = gates + ((size_t)(b * Tc + s * 64)) * 1536 + l;
  const ushort* zb = Z + ((size_t)(b * 1024 + tc + s * 64)) * 512 + l;
#pragma unroll 8
  for (int j = 0; j < 64; ++j) {
    const float iv = h2f(gb[(size_t)j * 1536]);
    const float fv = h2f(gb[(size_t)j * 1536 + 512]);
    const float gv = h2f(gb[(size_t)j * 1536 + 1024]);
    const float zv = bf2f(zb[(size_t)j * 512]);
    c = fmaf(fv, c, iv * gv);
    tile[tid][j] = sinf(zv) * c;
  }
  __syncthreads();
  const int col = tid & 63, rhalf = tid >> 6;
  const size_t obase = ((size_t)b * 512 + l0) * 1024 + (size_t)(tc + s * 64) + col;
#pragma unroll
  for (int p = 0; p < 64; ++p) {
    const int row = rhalf + p * 2;
    out[obase + (size_t)row * 1024] = tile[row][col];
  }
}

// ------------------------------------------------ launcher
extern "C" void kernel_launch(void* const* d_in, const int* in_sizes, int n_in,
                              void* d_out, int out_size, void* d_ws, size_t ws_size,
                              hipStream_t stream)
{
  const float* x  = (const float*)d_in[0];
  const float* W  = (const float*)d_in[1];
  const float* rb = (const float*)d_in[2];
  const float* wi = (const float*)d_in[3];
  const float* wf = (const float*)d_in[4];
  const float* wc = (const float*)d_in[5];
  const float* ri = (const float*)d_in[6];
  const float* rf = (const float*)d_in[7];
  const float* rc = (const float*)d_in[8];
  const float* bi = (const float*)d_in[9];
  const float* bfo = (const float*)d_in[10];
  const float* bc = (const float*)d_in[11];
  const float* il = (const float*)d_in[12];
  const float* ic = (const float*)d_in[13];
  float* out = (float*)d_out;

  char* ws = (char*)d_ws;
  size_t off = 0;
  auto alloc = [&](size_t bytes) -> void* {
    void* p = ws + off;
    off = (off + bytes + 255) & ~(size_t)255;
    return p;
  };
  ushort* z    = (ushort*)alloc((size_t)65536 * 512 * 2);   // 67.1 MB
  ushort* W1t  = (ushort*)alloc((size_t)512 * 512 * 2);
  ushort* W2t  = (ushort*)alloc((size_t)1536 * 1024 * 2);
  ushort* ilb  = (ushort*)alloc(512 * 2);
  float*  cbuf = (float*)alloc((size_t)64 * 512 * 4);
  float*  Aseg = (float*)alloc((size_t)64 * 16 * 512 * 4);  // 2 MB
  float*  Bseg = (float*)alloc((size_t)64 * 16 * 512 * 4);
  float*  cstart = (float*)alloc((size_t)64 * 16 * 512 * 4);
  const size_t fixed_end = off;
  ushort* xt   = (ushort*)alloc((size_t)65536 * 512 * 2);   // dead after K1
  ushort* gates = (ushort*)(ws + fixed_end);                // aliases xt region
  ushort* u    = (ushort*)d_out;                            // dead before k3c

  int Tc = 1024;
  while (Tc > 128 && fixed_end + (size_t)64 * Tc * 1536 * 2 > ws_size) Tc >>= 1;

  // prep
  transpose_cvt<<<dim3(16, 16), 256, 0, stream>>>(W, W1t, 512);
  transpose6<<<dim3(16, 16, 7), 256, 0, stream>>>(wi, ri, wf, rf, wc, rc, il, W2t, ilb);
  transpose_x<<<dim3(16, 8, 64), 256, 0, stream>>>(x, xt);

  k1_mfma<<<dim3(2048), 256, 0, stream>>>(xt, W1t, rb, u);
  ln_rows<<<16384, 256, 0, stream>>>(u, z);

  for (int tc = 0; tc < 1024; tc += Tc) {
    const int SEGc = Tc >> 6;
    const int nwg2 = 12 * 64 * (Tc >> 7);
    k2_mfma<<<dim3(nwg2), 256, 0, stream>>>(
        z, W2t, ilb, bi, bfo, bc, gates, tc, Tc, nwg2);
    k3a_seg<<<dim3(2, 64, SEGc), 256, 0, stream>>>(gates, Aseg, Bseg, Tc);
    k3b_comb<<<64, 512, 0, stream>>>(Aseg, Bseg, ic, cstart, cbuf, tc, Tc);
    k3c_emit<<<dim3(4, 64, SEGc), 128, 0, stream>>>(gates, z, cstart, out, tc, Tc);
  }
}

// Round 11
// 568.081 us; speedup vs baseline: 1.1546x; 1.1546x over previous
//
#include <hip/hip_runtime.h>
#include <hip/hip_bf16.h>
#include <hip/hip_fp16.h>
#include <cstdint>
#include <cstddef>

// B=64, D=512, T=1024, L=512
// prep:  xt[b][t][d] bf16 ; W1t[l][d] bf16 ; W2t[n=1536][k=1024] bf16 ; il bf16
// K1:    u = cos(xt @ rff_w + b)            (MFMA 128x128 BK=64 swizzled LDS)
// LN:    z = layernorm(u)                   (bf16, one wave per row)
// K2:    two block types (r8 loop structure, single-buffered, __syncthreads):
//          bx<4:  i,g GEMMs sharing A tile -> P = sigmoid(i)*tanh(g)  fp16
//          bx>=4: f GEMM                   -> F = sigmoid(f)          fp16
//        G2 layout [row][1024]: [0,512) = P, [512,1024) = F
// scan (segmented): k3a summaries -> k3b combine -> k3c emit + transpose
//
// LESSONS: (r4-r6) acc arrays are NOT SROA-promoted -> scratch RMW; use NAMED
// accumulators. (r8) XOR swizzle both-sides -> bank conflicts 2.5e7 -> 0.
// (r9 FAIL) loads in flight across raw s_barriers race (vmcnt is per-wave).
// (r10 FAIL) explicit dbuf halved blocks/CU 3->2; inter-block overlap (m114)
// already hid the stage latency. Keep single-buffer + __syncthreads + >=3
// blocks/CU; win via barrier amortization (more MFMA per barrier) instead.

typedef float f32x4 __attribute__((ext_vector_type(4)));
typedef short s16x8 __attribute__((ext_vector_type(8)));

__device__ __forceinline__ void gload_lds16(const void* g, void* l) {
  __builtin_amdgcn_global_load_lds(
      (const __attribute__((address_space(1))) void*)g,
      (__attribute__((address_space(3))) void*)l, 16, 0, 0);
}
__device__ __forceinline__ ushort f2bf(float f) {
  uint32_t u = __float_as_uint(f);
  return (ushort)((u + 0x7FFF + ((u >> 16) & 1)) >> 16);  // RNE
}
__device__ __forceinline__ float bf2f(ushort s) {
  return __uint_as_float(((uint32_t)s) << 16);
}
__device__ __forceinline__ ushort f2h(float f) {
  return __half_as_ushort(__float2half(f));
}
__device__ __forceinline__ float h2f(ushort s) {
  return __half2float(__ushort_as_half(s));
}

#define MF(d, a, b) d = __builtin_amdgcn_mfma_f32_16x16x32_bf16(a, b, d, 0, 0, 0);

// ------------------------------------------------ prep: W1 transpose (small)
__global__ __launch_bounds__(256) void transpose_cvt(
    const float* __restrict__ src, ushort* __restrict__ dst, int ld)
{
  __shared__ float tile[32][33];
  const int c0 = blockIdx.x * 32, r0 = blockIdx.y * 32;
  const int tx = threadIdx.x & 31, ty = threadIdx.x >> 5;
#pragma unroll
  for (int i = 0; i < 4; ++i)
    tile[ty + i * 8][tx] = src[(size_t)(r0 + ty + i * 8) * 512 + c0 + tx];
  __syncthreads();
#pragma unroll
  for (int i = 0; i < 4; ++i)
    dst[(size_t)(c0 + ty + i * 8) * ld + r0 + tx] = f2bf(tile[tx][ty + i * 8]);
}

// ------------------------------------------------ prep: 6 gate weights + il
__global__ __launch_bounds__(256) void transpose6(
    const float* __restrict__ s0, const float* __restrict__ s1,
    const float* __restrict__ s2, const float* __restrict__ s3,
    const float* __restrict__ s4, const float* __restrict__ s5,
    const float* __restrict__ il, ushort* __restrict__ W2t,
    ushort* __restrict__ ilb)
{
  const int z = blockIdx.z;
  if (z == 6) {
    if (blockIdx.x == 0 && blockIdx.y == 0) {
      ilb[threadIdx.x] = f2bf(il[threadIdx.x]);
      ilb[threadIdx.x + 256] = f2bf(il[threadIdx.x + 256]);
    }
    return;
  }
  const float* src = z == 0 ? s0 : z == 1 ? s1 : z == 2 ? s2
                   : z == 3 ? s3 : z == 4 ? s4 : s5;
  ushort* dst = W2t + (size_t)(z >> 1) * 512 * 1024 + (z & 1) * 512;
  __shared__ float tile[32][33];
  const int c0 = blockIdx.x * 32, r0 = blockIdx.y * 32;
  const int tx = threadIdx.x & 31, ty = threadIdx.x >> 5;
#pragma unroll
  for (int i = 0; i < 4; ++i)
    tile[ty + i * 8][tx] = src[(size_t)(r0 + ty + i * 8) * 512 + c0 + tx];
  __syncthreads();
#pragma unroll
  for (int i = 0; i < 4; ++i)
    dst[(size_t)(c0 + ty + i * 8) * 1024 + r0 + tx] = f2bf(tile[tx][ty + i * 8]);
}

// ------------------------------------------------ prep: x[b][d][t] -> xt[b][t][d]
__global__ __launch_bounds__(256) void transpose_x(
    const float* __restrict__ x, ushort* __restrict__ xt)
{
  __shared__ float tile[64][68];
  const int b = blockIdx.z;
  const int t0 = blockIdx.x * 64, d0 = blockIdx.y * 64;
  const float* src = x + ((size_t)b * 512 + d0) * 1024 + t0;
  const int lr_ = threadIdx.x >> 4, lc4 = (threadIdx.x & 15) * 4;
#pragma unroll
  for (int p = 0; p < 4; ++p) {
    const float4 v = *(const float4*)(src + (size_t)(lr_ + p * 16) * 1024 + lc4);
    *(float4*)&tile[lr_ + p * 16][lc4] = v;
  }
  __syncthreads();
  const int tt = threadIdx.x >> 2, dc = (threadIdx.x & 3) * 16;
  ushort* dst = xt + ((size_t)b * 1024 + t0 + tt) * 512 + d0 + dc;
  uint4 o1, o2;
  o1.x = (uint)f2bf(tile[dc + 0][tt]) | ((uint)f2bf(tile[dc + 1][tt]) << 16);
  o1.y = (uint)f2bf(tile[dc + 2][tt]) | ((uint)f2bf(tile[dc + 3][tt]) << 16);
  o1.z = (uint)f2bf(tile[dc + 4][tt]) | ((uint)f2bf(tile[dc + 5][tt]) << 16);
  o1.w = (uint)f2bf(tile[dc + 6][tt]) | ((uint)f2bf(tile[dc + 7][tt]) << 16);
  o2.x = (uint)f2bf(tile[dc + 8][tt]) | ((uint)f2bf(tile[dc + 9][tt]) << 16);
  o2.y = (uint)f2bf(tile[dc + 10][tt]) | ((uint)f2bf(tile[dc + 11][tt]) << 16);
  o2.z = (uint)f2bf(tile[dc + 12][tt]) | ((uint)f2bf(tile[dc + 13][tt]) << 16);
  o2.w = (uint)f2bf(tile[dc + 14][tt]) | ((uint)f2bf(tile[dc + 15][tt]) << 16);
  *(uint4*)(dst) = o1;
  *(uint4*)(dst + 8) = o2;
}

// ------------------------------------------------ K1 (r8-verified, unchanged)
__global__ __launch_bounds__(256, 2) void k1_mfma(
    const ushort* __restrict__ A, const ushort* __restrict__ Bt,
    const float* __restrict__ bias, ushort* __restrict__ U)
{
  __shared__ __align__(16) short As[128 * 64];
  __shared__ __align__(16) short Bs[128 * 64];
  const int tid = threadIdx.x;
  const int lane = tid & 63, wid = tid >> 6;
  const int orig = blockIdx.x;
  const int swz = (orig & 7) * 256 + (orig >> 3);
  const int n0 = (swz & 3) * 128, r0 = (swz >> 2) * 128;
  const int wr = wid >> 1, wc = wid & 1;
  const int fr = lane & 15, fq = lane >> 4;
  const int lr = lane >> 3;
  const int swz_el = ((lane & 7) ^ lr) * 8;

  const int RA = r0 + wid * 32 + lr;
  const ushort* pa0 = A + (size_t)(RA)      * 512 + swz_el;
  const ushort* pa1 = A + (size_t)(RA + 8)  * 512 + swz_el;
  const ushort* pa2 = A + (size_t)(RA + 16) * 512 + swz_el;
  const ushort* pa3 = A + (size_t)(RA + 24) * 512 + swz_el;
  const int RB = n0 + wid * 32 + lr;
  const ushort* pb0 = Bt + (size_t)(RB)      * 512 + swz_el;
  const ushort* pb1 = Bt + (size_t)(RB + 8)  * 512 + swz_el;
  const ushort* pb2 = Bt + (size_t)(RB + 16) * 512 + swz_el;
  const ushort* pb3 = Bt + (size_t)(RB + 24) * 512 + swz_el;
  char* dA = (char*)As + wid * 4096;
  char* dB = (char*)Bs + wid * 4096;

  const int so0 = fr * 64 + ((fq)     ^ (fr & 7)) * 8;
  const int so1 = fr * 64 + ((4 + fq) ^ (fr & 7)) * 8;

  f32x4 c00 = {0.f,0.f,0.f,0.f}, c01 = c00, c02 = c00, c03 = c00,
        c10 = c00, c11 = c00, c12 = c00, c13 = c00,
        c20 = c00, c21 = c00, c22 = c00, c23 = c00,
        c30 = c00, c31 = c00, c32 = c00, c33 = c00;

  for (int k0 = 0; k0 < 512; k0 += 64) {
    gload_lds16(pa0 + k0, dA);        gload_lds16(pa1 + k0, dA + 1024);
    gload_lds16(pa2 + k0, dA + 2048); gload_lds16(pa3 + k0, dA + 3072);
    gload_lds16(pb0 + k0, dB);        gload_lds16(pb1 + k0, dB + 1024);
    gload_lds16(pb2 + k0, dB + 2048); gload_lds16(pb3 + k0, dB + 3072);
    __syncthreads();
    const s16x8 a00 = *(const s16x8*)&As[wr * 4096 + 0 * 1024 + so0];
    const s16x8 a01 = *(const s16x8*)&As[wr * 4096 + 0 * 1024 + so1];
    const s16x8 a10 = *(const s16x8*)&As[wr * 4096 + 1 * 1024 + so0];
    const s16x8 a11 = *(const s16x8*)&As[wr * 4096 + 1 * 1024 + so1];
    const s16x8 a20 = *(const s16x8*)&As[wr * 4096 + 2 * 1024 + so0];
    const s16x8 a21 = *(const s16x8*)&As[wr * 4096 + 2 * 1024 + so1];
    const s16x8 a30 = *(const s16x8*)&As[wr * 4096 + 3 * 1024 + so0];
    const s16x8 a31 = *(const s16x8*)&As[wr * 4096 + 3 * 1024 + so1];
    const s16x8 b00 = *(const s16x8*)&Bs[wc * 4096 + 0 * 1024 + so0];
    const s16x8 b01 = *(const s16x8*)&Bs[wc * 4096 + 0 * 1024 + so1];
    const s16x8 b10 = *(const s16x8*)&Bs[wc * 4096 + 1 * 1024 + so0];
    const s16x8 b11 = *(const s16x8*)&Bs[wc * 4096 + 1 * 1024 + so1];
    const s16x8 b20 = *(const s16x8*)&Bs[wc * 4096 + 2 * 1024 + so0];
    const s16x8 b21 = *(const s16x8*)&Bs[wc * 4096 + 2 * 1024 + so1];
    const s16x8 b30 = *(const s16x8*)&Bs[wc * 4096 + 3 * 1024 + so0];
    const s16x8 b31 = *(const s16x8*)&Bs[wc * 4096 + 3 * 1024 + so1];
    MF(c00, a00, b00) MF(c01, a00, b10) MF(c02, a00, b20) MF(c03, a00, b30)
    MF(c10, a10, b00) MF(c11, a10, b10) MF(c12, a10, b20) MF(c13, a10, b30)
    MF(c20, a20, b00) MF(c21, a20, b10) MF(c22, a20, b20) MF(c23, a20, b30)
    MF(c30, a30, b00) MF(c31, a30, b10) MF(c32, a30, b20) MF(c33, a30, b30)
    MF(c00, a01, b01) MF(c01, a01, b11) MF(c02, a01, b21) MF(c03, a01, b31)
    MF(c10, a11, b01) MF(c11, a11, b11) MF(c12, a11, b21) MF(c13, a11, b31)
    MF(c20, a21, b01) MF(c21, a21, b11) MF(c22, a21, b21) MF(c23, a21, b31)
    MF(c30, a31, b01) MF(c31, a31, b11) MF(c32, a31, b21) MF(c33, a31, b31)
    __syncthreads();
  }

#define EPI1(cmn, m_, n_) { \
    const int col = n0 + wc * 64 + n_ * 16 + fr; \
    const float bv = bias[col]; \
    const int rbase = r0 + wr * 64 + m_ * 16 + fq * 4; \
    _Pragma("unroll") for (int j = 0; j < 4; ++j) \
      U[(size_t)(rbase + j) * 512 + col] = f2bf(cosf(cmn[j] + bv)); }
  EPI1(c00, 0, 0) EPI1(c01, 0, 1) EPI1(c02, 0, 2) EPI1(c03, 0, 3)
  EPI1(c10, 1, 0) EPI1(c11, 1, 1) EPI1(c12, 1, 2) EPI1(c13, 1, 3)
  EPI1(c20, 2, 0) EPI1(c21, 2, 1) EPI1(c22, 2, 2) EPI1(c23, 2, 3)
  EPI1(c30, 3, 0) EPI1(c31, 3, 1) EPI1(c32, 3, 2) EPI1(c33, 3, 3)
#undef EPI1
}

// ------------------------------------------------ LN: one wave per 512-row
__global__ __launch_bounds__(256) void ln_rows(
    const ushort* __restrict__ U, ushort* __restrict__ Z)
{
  const int row = blockIdx.x * 4 + (threadIdx.x >> 6);
  const int lane = threadIdx.x & 63;
  const size_t base = (size_t)row * 512 + lane * 8;
  const uint4 pk = *(const uint4*)(U + base);
  float v[8];
  v[0] = bf2f(pk.x & 0xffff); v[1] = bf2f(pk.x >> 16);
  v[2] = bf2f(pk.y & 0xffff); v[3] = bf2f(pk.y >> 16);
  v[4] = bf2f(pk.z & 0xffff); v[5] = bf2f(pk.z >> 16);
  v[6] = bf2f(pk.w & 0xffff); v[7] = bf2f(pk.w >> 16);
  float s = 0.f, s2 = 0.f;
#pragma unroll
  for (int j = 0; j < 8; ++j) { s += v[j]; s2 += v[j] * v[j]; }
#pragma unroll
  for (int m = 1; m < 64; m <<= 1) { s += __shfl_xor(s, m); s2 += __shfl_xor(s2, m); }
  const float mean = s * (1.f / 512.f);
  const float var = s2 * (1.f / 512.f) - mean * mean;
  const float inv = rsqrtf(var + 1e-5f);
  uint4 o;
  o.x = (uint)f2bf((v[0] - mean) * inv) | ((uint)f2bf((v[1] - mean) * inv) << 16);
  o.y = (uint)f2bf((v[2] - mean) * inv) | ((uint)f2bf((v[3] - mean) * inv) << 16);
  o.z = (uint)f2bf((v[4] - mean) * inv) | ((uint)f2bf((v[5] - mean) * inv) << 16);
  o.w = (uint)f2bf((v[6] - mean) * inv) | ((uint)f2bf((v[7] - mean) * inv) << 16);
  *(uint4*)(Z + base) = o;
}

// ------------------------------------------------ K2: two block types.
// bx<4: i,g GEMMs share the staged A tile (64 MFMA/barrier) -> P = sig*tanh.
// bx>=4: f GEMM (r8 block) -> F = sigmoid. G2[row][1024] = [P | F].
__global__ __launch_bounds__(256, 2) void k2_mfma(
    const ushort* __restrict__ Z, const ushort* __restrict__ Wt,
    const ushort* __restrict__ IL,
    const float* __restrict__ biv, const float* __restrict__ bfv,
    const float* __restrict__ bcv,
    ushort* __restrict__ G2, int tc, int Tc, int nwg)
{
  __shared__ __align__(16) short As[128 * 64];    // 16 KB
  __shared__ __align__(16) short Bs0[128 * 64];   // 16 KB
  __shared__ __align__(16) short Bs1[128 * 64];   // 16 KB (ig only)
  const int tid = threadIdx.x;
  const int lane = tid & 63, wid = tid >> 6;
  const int cpx = nwg >> 3;
  const int orig = blockIdx.x;
  const int swz = (orig & 7) * cpx + (orig >> 3);
  const int bx = swz & 7, by = swz >> 3;
  const int nb = Tc >> 7;
  const int b = by / nb, tb = by % nb;
  const int r0g = b * 1024 + tc + tb * 128;
  const int r0c = b * Tc + tb * 128;
  const bool isig = bx < 4;
  const int n0 = (bx & 3) * 128;
  const int wr = wid >> 1, wc = wid & 1;
  const int fr = lane & 15, fq = lane >> 4;
  const int lr = lane >> 3;
  const int swz_el = ((lane & 7) ^ lr) * 8;

  const int R0 = r0g + wid * 32 + lr;
  const ushort* pa0 = Z + (size_t)(R0)      * 512 + swz_el;
  const ushort* pa1 = Z + (size_t)(R0 + 8)  * 512 + swz_el;
  const ushort* pa2 = Z + (size_t)(R0 + 16) * 512 + swz_el;
  const ushort* pa3 = Z + (size_t)(R0 + 24) * 512 + swz_el;
  const ushort* ph0 = ((((R0)      & 1023) == 0) ? IL : (Z + (size_t)(R0 - 1)  * 512)) + swz_el;
  const ushort* ph1 = ((((R0 + 8)  & 1023) == 0) ? IL : (Z + (size_t)(R0 + 7)  * 512)) + swz_el;
  const ushort* ph2 = ((((R0 + 16) & 1023) == 0) ? IL : (Z + (size_t)(R0 + 15) * 512)) + swz_el;
  const ushort* ph3 = ((((R0 + 24) & 1023) == 0) ? IL : (Z + (size_t)(R0 + 23) * 512)) + swz_el;
  // panel 0: gate i (rows [0,512)) for ig-blocks, gate f (rows [512,1024)) else
  const int RB0 = (isig ? n0 : 512 + n0) + wid * 32 + lr;
  const ushort* pb0 = Wt + (size_t)(RB0)      * 1024 + swz_el;
  const ushort* pb1 = Wt + (size_t)(RB0 + 8)  * 1024 + swz_el;
  const ushort* pb2 = Wt + (size_t)(RB0 + 16) * 1024 + swz_el;
  const ushort* pb3 = Wt + (size_t)(RB0 + 24) * 1024 + swz_el;
  // panel 1: gate g (rows [1024,1536)) — ig-blocks only
  const int RB1 = 1024 + n0 + wid * 32 + lr;
  const ushort* pq0 = Wt + (size_t)(RB1)      * 1024 + swz_el;
  const ushort* pq1 = Wt + (size_t)(RB1 + 8)  * 1024 + swz_el;
  const ushort* pq2 = Wt + (size_t)(RB1 + 16) * 1024 + swz_el;
  const ushort* pq3 = Wt + (size_t)(RB1 + 24) * 1024 + swz_el;

  const int so0 = fr * 64 + ((fq)     ^ (fr & 7)) * 8;
  const int so1 = fr * 64 + ((4 + fq) ^ (fr & 7)) * 8;

  f32x4 zz = {0.f,0.f,0.f,0.f};
  f32x4 c00=zz,c01=zz,c02=zz,c03=zz, c10=zz,c11=zz,c12=zz,c13=zz,
        c20=zz,c21=zz,c22=zz,c23=zz, c30=zz,c31=zz,c32=zz,c33=zz;
  f32x4 d00=zz,d01=zz,d02=zz,d03=zz, d10=zz,d11=zz,d12=zz,d13=zz,
        d20=zz,d21=zz,d22=zz,d23=zz, d30=zz,d31=zz,d32=zz,d33=zz;

#define STG8(P0,P1,P2,P3, KO, DST) { \
    char* d_ = (char*)(DST) + wid * 4096; \
    gload_lds16((P0) + (KO), d_);        gload_lds16((P1) + (KO), d_ + 1024); \
    gload_lds16((P2) + (KO), d_ + 2048); gload_lds16((P3) + (KO), d_ + 3072); }

#define RDA(SO) \
    const s16x8 fa0 = *(const s16x8*)&As[wr * 4096 + 0 * 1024 + (SO)]; \
    const s16x8 fa1 = *(const s16x8*)&As[wr * 4096 + 1 * 1024 + (SO)]; \
    const s16x8 fa2 = *(const s16x8*)&As[wr * 4096 + 2 * 1024 + (SO)]; \
    const s16x8 fa3 = *(const s16x8*)&As[wr * 4096 + 3 * 1024 + (SO)];

#define RDB(BS, SO) \
    const s16x8 fb0 = *(const s16x8*)&(BS)[wc * 4096 + 0 * 1024 + (SO)]; \
    const s16x8 fb1 = *(const s16x8*)&(BS)[wc * 4096 + 1 * 1024 + (SO)]; \
    const s16x8 fb2 = *(const s16x8*)&(BS)[wc * 4096 + 2 * 1024 + (SO)]; \
    const s16x8 fb3 = *(const s16x8*)&(BS)[wc * 4096 + 3 * 1024 + (SO)];

#define MMC \
    MF(c00,fa0,fb0) MF(c01,fa0,fb1) MF(c02,fa0,fb2) MF(c03,fa0,fb3) \
    MF(c10,fa1,fb0) MF(c11,fa1,fb1) MF(c12,fa1,fb2) MF(c13,fa1,fb3) \
    MF(c20,fa2,fb0) MF(c21,fa2,fb1) MF(c22,fa2,fb2) MF(c23,fa2,fb3) \
    MF(c30,fa3,fb0) MF(c31,fa3,fb1) MF(c32,fa3,fb2) MF(c33,fa3,fb3)

#define MMD \
    MF(d00,fa0,fb0) MF(d01,fa0,fb1) MF(d02,fa0,fb2) MF(d03,fa0,fb3) \
    MF(d10,fa1,fb0) MF(d11,fa1,fb1) MF(d12,fa1,fb2) MF(d13,fa1,fb3) \
    MF(d20,fa2,fb0) MF(d21,fa2,fb1) MF(d22,fa2,fb2) MF(d23,fa2,fb3) \
    MF(d30,fa3,fb0) MF(d31,fa3,fb1) MF(d32,fa3,fb2) MF(d33,fa3,fb3)

#define KSTEP(SO_) { \
    RDA(SO_) \
    { RDB(Bs0, SO_) MMC } \
    if (isig) { RDB(Bs1, SO_) MMD } }

  // half 1: A = z_t (rows R0), B k-cols [0,512)
  for (int k0 = 0; k0 < 512; k0 += 64) {
    STG8(pa0, pa1, pa2, pa3, k0, As)
    STG8(pb0, pb1, pb2, pb3, k0, Bs0)
    if (isig) { STG8(pq0, pq1, pq2, pq3, k0, Bs1) }
    __syncthreads();
    KSTEP(so0)
    KSTEP(so1)
    __syncthreads();
  }
  // half 2: A = z_prev (rows R0-1 / IL), B k-cols [512,1024)
  for (int k0 = 0; k0 < 512; k0 += 64) {
    STG8(ph0, ph1, ph2, ph3, k0, As)
    STG8(pb0, pb1, pb2, pb3, 512 + k0, Bs0)
    if (isig) { STG8(pq0, pq1, pq2, pq3, 512 + k0, Bs1) }
    __syncthreads();
    KSTEP(so0)
    KSTEP(so1)
    __syncthreads();
  }
#undef KSTEP
#undef MMD
#undef MMC
#undef RDB
#undef RDA
#undef STG8

  if (isig) {
    // P = sigmoid(i + bi) * tanh(g + bc) -> cols [0,512)
#define EPI(cmn, dmn, m_, n_) { \
    const int col = n0 + wc * 64 + n_ * 16 + fr; \
    const float bvi = biv[col], bvc = bcv[col]; \
    const int rbase = wr * 64 + m_ * 16 + fq * 4; \
    _Pragma("unroll") for (int j = 0; j < 4; ++j) { \
      const float iv = 1.f / (1.f + __expf(-(cmn[j] + bvi))); \
      const float gv = 2.f / (1.f + __expf(-2.f * (dmn[j] + bvc))) - 1.f; \
      G2[(size_t)(r0c + rbase + j) * 1024 + col] = f2h(iv * gv); } }
    EPI(c00, d00, 0, 0) EPI(c01, d01, 0, 1) EPI(c02, d02, 0, 2) EPI(c03, d03, 0, 3)
    EPI(c10, d10, 1, 0) EPI(c11, d11, 1, 1) EPI(c12, d12, 1, 2) EPI(c13, d13, 1, 3)
    EPI(c20, d20, 2, 0) EPI(c21, d21, 2, 1) EPI(c22, d22, 2, 2) EPI(c23, d23, 2, 3)
    EPI(c30, d30, 3, 0) EPI(c31, d31, 3, 1) EPI(c32, d32, 3, 2) EPI(c33, d33, 3, 3)
#undef EPI
  } else {
    // F = sigmoid(f + bf) -> cols [512,1024)
#define EPI(cmn, m_, n_) { \
    const int col = n0 + wc * 64 + n_ * 16 + fr; \
    const float bv = bfv[col]; \
    const int rbase = wr * 64 + m_ * 16 + fq * 4; \
    _Pragma("unroll") for (int j = 0; j < 4; ++j) { \
      const float fv = 1.f / (1.f + __expf(-(cmn[j] + bv))); \
      G2[(size_t)(r0c + rbase + j) * 1024 + 512 + col] = f2h(fv); } }
    EPI(c00, 0, 0) EPI(c01, 0, 1) EPI(c02, 0, 2) EPI(c03, 0, 3)
    EPI(c10, 1, 0) EPI(c11, 1, 1) EPI(c12, 1, 2) EPI(c13, 1, 3)
    EPI(c20, 2, 0) EPI(c21, 2, 1) EPI(c22, 2, 2) EPI(c23, 2, 3)
    EPI(c30, 3, 0) EPI(c31, 3, 1) EPI(c32, 3, 2) EPI(c33, 3, 3)
#undef EPI
  }
}

// ------------------------------------------------ scan phase A
__global__ __launch_bounds__(256) void k3a_seg(
    const ushort* __restrict__ G2, float* __restrict__ Aseg,
    float* __restrict__ Bseg, int Tc)
{
  const int l = blockIdx.x * 256 + threadIdx.x;
  const int b = blockIdx.y, s = blockIdx.z;
  const int SEGc = Tc >> 6;
  const ushort* gb = G2 + ((size_t)(b * Tc + s * 64)) * 1024 + l;
  float A = 1.f, c = 0.f;
#pragma unroll 8
  for (int j = 0; j < 64; ++j) {
    const float P = h2f(gb[(size_t)j * 1024]);
    const float F = h2f(gb[(size_t)j * 1024 + 512]);
    A *= F;
    c = fmaf(F, c, P);
  }
  const size_t o = (size_t)(b * SEGc + s) * 512 + l;
  Aseg[o] = A;
  Bseg[o] = c;
}

// ------------------------------------------------ scan phase B
__global__ __launch_bounds__(512) void k3b_comb(
    const float* __restrict__ Aseg, const float* __restrict__ Bseg,
    const float* __restrict__ initc, float* __restrict__ cstart,
    float* __restrict__ cbuf, int tc, int Tc)
{
  const int b = blockIdx.x, l = threadIdx.x;
  const int SEGc = Tc >> 6;
  float c = (tc == 0) ? initc[l] : cbuf[b * 512 + l];
  for (int s = 0; s < SEGc; ++s) {
    const size_t o = (size_t)(b * SEGc + s) * 512 + l;
    cstart[o] = c;
    c = fmaf(Aseg[o], c, Bseg[o]);
  }
  cbuf[b * 512 + l] = c;
}

// ------------------------------------------------ scan phase C
__global__ __launch_bounds__(128) void k3c_emit(
    const ushort* __restrict__ G2, const ushort* __restrict__ Z,
    const float* __restrict__ cstart, float* __restrict__ out,
    int tc, int Tc)
{
  __shared__ float tile[128][65];
  const int tid = threadIdx.x;
  const int l0 = blockIdx.x * 128;
  const int b = blockIdx.y, s = blockIdx.z;
  const int SEGc = Tc >> 6;
  const int l = l0 + tid;

  float c = cstart[(size_t)(b * SEGc + s) * 512 + l];
  const ushort* gb = G2 + ((size_t)(b * Tc + s * 64)) * 1024 + l;
  const ushort* zb = Z + ((size_t)(b * 1024 + tc + s * 64)) * 512 + l;
#pragma unroll 8
  for (int j = 0; j < 64; ++j) {
    const float P = h2f(gb[(size_t)j * 1024]);
    const float F = h2f(gb[(size_t)j * 1024 + 512]);
    const float zv = bf2f(zb[(size_t)j * 512]);
    c = fmaf(F, c, P);
    tile[tid][j] = sinf(zv) * c;
  }
  __syncthreads();
  const int col = tid & 63, rhalf = tid >> 6;
  const size_t obase = ((size_t)b * 512 + l0) * 1024 + (size_t)(tc + s * 64) + col;
#pragma unroll
  for (int p = 0; p < 64; ++p) {
    const int row = rhalf + p * 2;
    out[obase + (size_t)row * 1024] = tile[row][col];
  }
}

// ------------------------------------------------ launcher
extern "C" void kernel_launch(void* const* d_in, const int* in_sizes, int n_in,
                              void* d_out, int out_size, void* d_ws, size_t ws_size,
                              hipStream_t stream)
{
  const float* x  = (const float*)d_in[0];
  const float* W  = (const float*)d_in[1];
  const float* rb = (const float*)d_in[2];
  const float* wi = (const float*)d_in[3];
  const float* wf = (const float*)d_in[4];
  const float* wc = (const float*)d_in[5];
  const float* ri = (const float*)d_in[6];
  const float* rf = (const float*)d_in[7];
  const float* rc = (const float*)d_in[8];
  const float* bi = (const float*)d_in[9];
  const float* bfo = (const float*)d_in[10];
  const float* bc = (const float*)d_in[11];
  const float* il = (const float*)d_in[12];
  const float* ic = (const float*)d_in[13];
  float* out = (float*)d_out;

  char* ws = (char*)d_ws;
  size_t off = 0;
  auto alloc = [&](size_t bytes) -> void* {
    void* p = ws + off;
    off = (off + bytes + 255) & ~(size_t)255;
    return p;
  };
  ushort* z    = (ushort*)alloc((size_t)65536 * 512 * 2);   // 67.1 MB
  ushort* W1t  = (ushort*)alloc((size_t)512 * 512 * 2);
  ushort* W2t  = (ushort*)alloc((size_t)1536 * 1024 * 2);
  ushort* ilb  = (ushort*)alloc(512 * 2);
  float*  cbuf = (float*)alloc((size_t)64 * 512 * 4);
  float*  Aseg = (float*)alloc((size_t)64 * 16 * 512 * 4);  // 2 MB
  float*  Bseg = (float*)alloc((size_t)64 * 16 * 512 * 4);
  float*  cstart = (float*)alloc((size_t)64 * 16 * 512 * 4);
  const size_t fixed_end = off;
  ushort* xt   = (ushort*)alloc((size_t)65536 * 512 * 2);   // dead after K1
  ushort* G2   = (ushort*)(ws + fixed_end);                 // aliases xt region
  ushort* u    = (ushort*)d_out;                            // dead before k3c

  int Tc = 1024;
  while (Tc > 128 && fixed_end + (size_t)64 * Tc * 1024 * 2 > ws_size) Tc >>= 1;

  // prep
  transpose_cvt<<<dim3(16, 16), 256, 0, stream>>>(W, W1t, 512);
  transpose6<<<dim3(16, 16, 7), 256, 0, stream>>>(wi, ri, wf, rf, wc, rc, il, W2t, ilb);
  transpose_x<<<dim3(16, 8, 64), 256, 0, stream>>>(x, xt);

  k1_mfma<<<dim3(2048), 256, 0, stream>>>(xt, W1t, rb, u);
  ln_rows<<<16384, 256, 0, stream>>>(u, z);

  for (int tc = 0; tc < 1024; tc += Tc) {
    const int SEGc = Tc >> 6;
    const int nwg2 = 8 * 64 * (Tc >> 7);
    k2_mfma<<<dim3(nwg2), 256, 0, stream>>>(
        z, W2t, ilb, bi, bfo, bc, G2, tc, Tc, nwg2);
    k3a_seg<<<dim3(2, 64, SEGc), 256, 0, stream>>>(G2, Aseg, Bseg, Tc);
    k3b_comb<<<64, 512, 0, stream>>>(Aseg, Bseg, ic, cstart, cbuf, tc, Tc);
    k3c_emit<<<dim3(4, 64, SEGc), 128, 0, stream>>>(G2, z, cstart, out, tc, Tc);
  }
}

// Round 12
// 534.912 us; speedup vs baseline: 1.2262x; 1.0620x over previous
//
#include <hip/hip_runtime.h>
#include <hip/hip_bf16.h>
#include <hip/hip_fp16.h>
#include <cstdint>
#include <cstddef>

// B=64, D=512, T=1024, L=512
// prep:  xt[b][t][d] bf16 ; W1t[l][d] bf16 ; W2t[n=1536][k=1024] bf16 ; il bf16
// K1:    u = cos(xt @ rff_w + b)            (MFMA 128x128 BK=64 swizzled LDS)
// LN:    z = layernorm(u)                   (bf16, one wave per row)
// K2:    uniform 6-block decomposition per 128-row tile (all 64 MFMA/step):
//          bx<4:  i,g GEMMs sharing A tile -> P = sigmoid(i)*tanh(g)  fp16
//          bx 4,5: f GEMM over TWO 128-col slices sharing A -> F      fp16
//        G2 layout [row][1024]: [0,512) = P, [512,1024) = F
// scan (segmented): k3a summaries -> k3b combine -> k3c emit + transpose
//
// LESSONS: (r4-r6) acc arrays are NOT SROA-promoted -> scratch RMW; use NAMED
// accumulators. (r8) XOR swizzle both-sides -> bank conflicts 2.5e7 -> 0.
// (r9 FAIL) loads in flight across raw s_barriers race (vmcnt is per-wave;
// s_barrier is not an IR memory fence). (r10 FAIL) explicit dbuf halved
// blocks/CU 3->2; inter-block overlap (m114) already hid stage latency.
// (r11) ig/f imbalance -> r12 uniform pairing.

typedef float f32x4 __attribute__((ext_vector_type(4)));
typedef short s16x8 __attribute__((ext_vector_type(8)));

__device__ __forceinline__ void gload_lds16(const void* g, void* l) {
  __builtin_amdgcn_global_load_lds(
      (const __attribute__((address_space(1))) void*)g,
      (__attribute__((address_space(3))) void*)l, 16, 0, 0);
}
__device__ __forceinline__ ushort f2bf(float f) {
  uint32_t u = __float_as_uint(f);
  return (ushort)((u + 0x7FFF + ((u >> 16) & 1)) >> 16);  // RNE
}
__device__ __forceinline__ float bf2f(ushort s) {
  return __uint_as_float(((uint32_t)s) << 16);
}
__device__ __forceinline__ ushort f2h(float f) {
  return __half_as_ushort(__float2half(f));
}
__device__ __forceinline__ float h2f(ushort s) {
  return __half2float(__ushort_as_half(s));
}

#define MF(d, a, b) d = __builtin_amdgcn_mfma_f32_16x16x32_bf16(a, b, d, 0, 0, 0);

// ------------------------------------------------ prep: 6 gate weights + W1 + il
__global__ __launch_bounds__(256) void transpose8(
    const float* __restrict__ s0, const float* __restrict__ s1,
    const float* __restrict__ s2, const float* __restrict__ s3,
    const float* __restrict__ s4, const float* __restrict__ s5,
    const float* __restrict__ il, const float* __restrict__ W1,
    ushort* __restrict__ W2t, ushort* __restrict__ ilb,
    ushort* __restrict__ W1t)
{
  const int z = blockIdx.z;
  if (z == 6) {
    if (blockIdx.x == 0 && blockIdx.y == 0) {
      ilb[threadIdx.x] = f2bf(il[threadIdx.x]);
      ilb[threadIdx.x + 256] = f2bf(il[threadIdx.x + 256]);
    }
    return;
  }
  const float* src = z == 0 ? s0 : z == 1 ? s1 : z == 2 ? s2
                   : z == 3 ? s3 : z == 4 ? s4 : z == 5 ? s5 : W1;
  ushort* dst = (z == 7) ? W1t
              : W2t + (size_t)(z >> 1) * 512 * 1024 + (z & 1) * 512;
  const int ld = (z == 7) ? 512 : 1024;
  __shared__ float tile[32][33];
  const int c0 = blockIdx.x * 32, r0 = blockIdx.y * 32;
  const int tx = threadIdx.x & 31, ty = threadIdx.x >> 5;
#pragma unroll
  for (int i = 0; i < 4; ++i)
    tile[ty + i * 8][tx] = src[(size_t)(r0 + ty + i * 8) * 512 + c0 + tx];
  __syncthreads();
#pragma unroll
  for (int i = 0; i < 4; ++i)
    dst[(size_t)(c0 + ty + i * 8) * ld + r0 + tx] = f2bf(tile[tx][ty + i * 8]);
}

// ------------------------------------------------ prep: x[b][d][t] -> xt[b][t][d]
__global__ __launch_bounds__(256) void transpose_x(
    const float* __restrict__ x, ushort* __restrict__ xt)
{
  __shared__ float tile[64][68];
  const int b = blockIdx.z;
  const int t0 = blockIdx.x * 64, d0 = blockIdx.y * 64;
  const float* src = x + ((size_t)b * 512 + d0) * 1024 + t0;
  const int lr_ = threadIdx.x >> 4, lc4 = (threadIdx.x & 15) * 4;
#pragma unroll
  for (int p = 0; p < 4; ++p) {
    const float4 v = *(const float4*)(src + (size_t)(lr_ + p * 16) * 1024 + lc4);
    *(float4*)&tile[lr_ + p * 16][lc4] = v;
  }
  __syncthreads();
  const int tt = threadIdx.x >> 2, dc = (threadIdx.x & 3) * 16;
  ushort* dst = xt + ((size_t)b * 1024 + t0 + tt) * 512 + d0 + dc;
  uint4 o1, o2;
  o1.x = (uint)f2bf(tile[dc + 0][tt]) | ((uint)f2bf(tile[dc + 1][tt]) << 16);
  o1.y = (uint)f2bf(tile[dc + 2][tt]) | ((uint)f2bf(tile[dc + 3][tt]) << 16);
  o1.z = (uint)f2bf(tile[dc + 4][tt]) | ((uint)f2bf(tile[dc + 5][tt]) << 16);
  o1.w = (uint)f2bf(tile[dc + 6][tt]) | ((uint)f2bf(tile[dc + 7][tt]) << 16);
  o2.x = (uint)f2bf(tile[dc + 8][tt]) | ((uint)f2bf(tile[dc + 9][tt]) << 16);
  o2.y = (uint)f2bf(tile[dc + 10][tt]) | ((uint)f2bf(tile[dc + 11][tt]) << 16);
  o2.z = (uint)f2bf(tile[dc + 12][tt]) | ((uint)f2bf(tile[dc + 13][tt]) << 16);
  o2.w = (uint)f2bf(tile[dc + 14][tt]) | ((uint)f2bf(tile[dc + 15][tt]) << 16);
  *(uint4*)(dst) = o1;
  *(uint4*)(dst + 8) = o2;
}

// ------------------------------------------------ K1 (r8-verified, unchanged)
__global__ __launch_bounds__(256, 2) void k1_mfma(
    const ushort* __restrict__ A, const ushort* __restrict__ Bt,
    const float* __restrict__ bias, ushort* __restrict__ U)
{
  __shared__ __align__(16) short As[128 * 64];
  __shared__ __align__(16) short Bs[128 * 64];
  const int tid = threadIdx.x;
  const int lane = tid & 63, wid = tid >> 6;
  const int orig = blockIdx.x;
  const int swz = (orig & 7) * 256 + (orig >> 3);
  const int n0 = (swz & 3) * 128, r0 = (swz >> 2) * 128;
  const int wr = wid >> 1, wc = wid & 1;
  const int fr = lane & 15, fq = lane >> 4;
  const int lr = lane >> 3;
  const int swz_el = ((lane & 7) ^ lr) * 8;

  const int RA = r0 + wid * 32 + lr;
  const ushort* pa0 = A + (size_t)(RA)      * 512 + swz_el;
  const ushort* pa1 = A + (size_t)(RA + 8)  * 512 + swz_el;
  const ushort* pa2 = A + (size_t)(RA + 16) * 512 + swz_el;
  const ushort* pa3 = A + (size_t)(RA + 24) * 512 + swz_el;
  const int RB = n0 + wid * 32 + lr;
  const ushort* pb0 = Bt + (size_t)(RB)      * 512 + swz_el;
  const ushort* pb1 = Bt + (size_t)(RB + 8)  * 512 + swz_el;
  const ushort* pb2 = Bt + (size_t)(RB + 16) * 512 + swz_el;
  const ushort* pb3 = Bt + (size_t)(RB + 24) * 512 + swz_el;
  char* dA = (char*)As + wid * 4096;
  char* dB = (char*)Bs + wid * 4096;

  const int so0 = fr * 64 + ((fq)     ^ (fr & 7)) * 8;
  const int so1 = fr * 64 + ((4 + fq) ^ (fr & 7)) * 8;

  f32x4 c00 = {0.f,0.f,0.f,0.f}, c01 = c00, c02 = c00, c03 = c00,
        c10 = c00, c11 = c00, c12 = c00, c13 = c00,
        c20 = c00, c21 = c00, c22 = c00, c23 = c00,
        c30 = c00, c31 = c00, c32 = c00, c33 = c00;

  for (int k0 = 0; k0 < 512; k0 += 64) {
    gload_lds16(pa0 + k0, dA);        gload_lds16(pa1 + k0, dA + 1024);
    gload_lds16(pa2 + k0, dA + 2048); gload_lds16(pa3 + k0, dA + 3072);
    gload_lds16(pb0 + k0, dB);        gload_lds16(pb1 + k0, dB + 1024);
    gload_lds16(pb2 + k0, dB + 2048); gload_lds16(pb3 + k0, dB + 3072);
    __syncthreads();
    const s16x8 a00 = *(const s16x8*)&As[wr * 4096 + 0 * 1024 + so0];
    const s16x8 a01 = *(const s16x8*)&As[wr * 4096 + 0 * 1024 + so1];
    const s16x8 a10 = *(const s16x8*)&As[wr * 4096 + 1 * 1024 + so0];
    const s16x8 a11 = *(const s16x8*)&As[wr * 4096 + 1 * 1024 + so1];
    const s16x8 a20 = *(const s16x8*)&As[wr * 4096 + 2 * 1024 + so0];
    const s16x8 a21 = *(const s16x8*)&As[wr * 4096 + 2 * 1024 + so1];
    const s16x8 a30 = *(const s16x8*)&As[wr * 4096 + 3 * 1024 + so0];
    const s16x8 a31 = *(const s16x8*)&As[wr * 4096 + 3 * 1024 + so1];
    const s16x8 b00 = *(const s16x8*)&Bs[wc * 4096 + 0 * 1024 + so0];
    const s16x8 b01 = *(const s16x8*)&Bs[wc * 4096 + 0 * 1024 + so1];
    const s16x8 b10 = *(const s16x8*)&Bs[wc * 4096 + 1 * 1024 + so0];
    const s16x8 b11 = *(const s16x8*)&Bs[wc * 4096 + 1 * 1024 + so1];
    const s16x8 b20 = *(const s16x8*)&Bs[wc * 4096 + 2 * 1024 + so0];
    const s16x8 b21 = *(const s16x8*)&Bs[wc * 4096 + 2 * 1024 + so1];
    const s16x8 b30 = *(const s16x8*)&Bs[wc * 4096 + 3 * 1024 + so0];
    const s16x8 b31 = *(const s16x8*)&Bs[wc * 4096 + 3 * 1024 + so1];
    MF(c00, a00, b00) MF(c01, a00, b10) MF(c02, a00, b20) MF(c03, a00, b30)
    MF(c10, a10, b00) MF(c11, a10, b10) MF(c12, a10, b20) MF(c13, a10, b30)
    MF(c20, a20, b00) MF(c21, a20, b10) MF(c22, a20, b20) MF(c23, a20, b30)
    MF(c30, a30, b00) MF(c31, a30, b10) MF(c32, a30, b20) MF(c33, a30, b30)
    MF(c00, a01, b01) MF(c01, a01, b11) MF(c02, a01, b21) MF(c03, a01, b31)
    MF(c10, a11, b01) MF(c11, a11, b11) MF(c12, a11, b21) MF(c13, a11, b31)
    MF(c20, a21, b01) MF(c21, a21, b11) MF(c22, a21, b21) MF(c23, a21, b31)
    MF(c30, a31, b01) MF(c31, a31, b11) MF(c32, a31, b21) MF(c33, a31, b31)
    __syncthreads();
  }

#define EPI1(cmn, m_, n_) { \
    const int col = n0 + wc * 64 + n_ * 16 + fr; \
    const float bv = bias[col]; \
    const int rbase = r0 + wr * 64 + m_ * 16 + fq * 4; \
    _Pragma("unroll") for (int j = 0; j < 4; ++j) \
      U[(size_t)(rbase + j) * 512 + col] = f2bf(cosf(cmn[j] + bv)); }
  EPI1(c00, 0, 0) EPI1(c01, 0, 1) EPI1(c02, 0, 2) EPI1(c03, 0, 3)
  EPI1(c10, 1, 0) EPI1(c11, 1, 1) EPI1(c12, 1, 2) EPI1(c13, 1, 3)
  EPI1(c20, 2, 0) EPI1(c21, 2, 1) EPI1(c22, 2, 2) EPI1(c23, 2, 3)
  EPI1(c30, 3, 0) EPI1(c31, 3, 1) EPI1(c32, 3, 2) EPI1(c33, 3, 3)
#undef EPI1
}

// ------------------------------------------------ LN: one wave per 512-row
__global__ __launch_bounds__(256) void ln_rows(
    const ushort* __restrict__ U, ushort* __restrict__ Z)
{
  const int row = blockIdx.x * 4 + (threadIdx.x >> 6);
  const int lane = threadIdx.x & 63;
  const size_t base = (size_t)row * 512 + lane * 8;
  const uint4 pk = *(const uint4*)(U + base);
  float v[8];
  v[0] = bf2f(pk.x & 0xffff); v[1] = bf2f(pk.x >> 16);
  v[2] = bf2f(pk.y & 0xffff); v[3] = bf2f(pk.y >> 16);
  v[4] = bf2f(pk.z & 0xffff); v[5] = bf2f(pk.z >> 16);
  v[6] = bf2f(pk.w & 0xffff); v[7] = bf2f(pk.w >> 16);
  float s = 0.f, s2 = 0.f;
#pragma unroll
  for (int j = 0; j < 8; ++j) { s += v[j]; s2 += v[j] * v[j]; }
#pragma unroll
  for (int m = 1; m < 64; m <<= 1) { s += __shfl_xor(s, m); s2 += __shfl_xor(s2, m); }
  const float mean = s * (1.f / 512.f);
  const float var = s2 * (1.f / 512.f) - mean * mean;
  const float inv = rsqrtf(var + 1e-5f);
  uint4 o;
  o.x = (uint)f2bf((v[0] - mean) * inv) | ((uint)f2bf((v[1] - mean) * inv) << 16);
  o.y = (uint)f2bf((v[2] - mean) * inv) | ((uint)f2bf((v[3] - mean) * inv) << 16);
  o.z = (uint)f2bf((v[4] - mean) * inv) | ((uint)f2bf((v[5] - mean) * inv) << 16);
  o.w = (uint)f2bf((v[6] - mean) * inv) | ((uint)f2bf((v[7] - mean) * inv) << 16);
  *(uint4*)(Z + base) = o;
}

// ------------------------------------------------ K2: uniform 6 blocks per tile.
// bx<4: (i,g)[n0=bx*128] -> P. bx in {4,5}: f over cols [fb*256, fb*256+256)
// as two 128-slices (c accs / d accs). All blocks: 1 A stage + 2 B panels,
// 64 MFMA per barrier pair, 48 KB LDS (3 blocks/CU).
__global__ __launch_bounds__(256, 2) void k2_mfma(
    const ushort* __restrict__ Z, const ushort* __restrict__ Wt,
    const ushort* __restrict__ IL,
    const float* __restrict__ biv, const float* __restrict__ bfv,
    const float* __restrict__ bcv,
    ushort* __restrict__ G2, int tc, int Tc, int nwg)
{
  __shared__ __align__(16) short As[128 * 64];    // 16 KB
  __shared__ __align__(16) short Bs0[128 * 64];   // 16 KB
  __shared__ __align__(16) short Bs1[128 * 64];   // 16 KB
  const int tid = threadIdx.x;
  const int lane = tid & 63, wid = tid >> 6;
  const int cpx = nwg >> 3;
  const int orig = blockIdx.x;
  const int swz = (orig & 7) * cpx + (orig >> 3);
  const int bx = swz % 6, by = swz / 6;
  const int nb = Tc >> 7;
  const int b = by / nb, tb = by % nb;
  const int r0g = b * 1024 + tc + tb * 128;
  const int r0c = b * Tc + tb * 128;
  const bool isig = bx < 4;
  const int n0 = isig ? bx * 128 : 0;
  const int fb = bx - 4;                       // 0/1 for f-blocks
  const int wr = wid >> 1, wc = wid & 1;
  const int fr = lane & 15, fq = lane >> 4;
  const int lr = lane >> 3;
  const int swz_el = ((lane & 7) ^ lr) * 8;

  const int R0 = r0g + wid * 32 + lr;
  const ushort* pa0 = Z + (size_t)(R0)      * 512 + swz_el;
  const ushort* pa1 = Z + (size_t)(R0 + 8)  * 512 + swz_el;
  const ushort* pa2 = Z + (size_t)(R0 + 16) * 512 + swz_el;
  const ushort* pa3 = Z + (size_t)(R0 + 24) * 512 + swz_el;
  const ushort* ph0 = ((((R0)      & 1023) == 0) ? IL : (Z + (size_t)(R0 - 1)  * 512)) + swz_el;
  const ushort* ph1 = ((((R0 + 8)  & 1023) == 0) ? IL : (Z + (size_t)(R0 + 7)  * 512)) + swz_el;
  const ushort* ph2 = ((((R0 + 16) & 1023) == 0) ? IL : (Z + (size_t)(R0 + 15) * 512)) + swz_el;
  const ushort* ph3 = ((((R0 + 24) & 1023) == 0) ? IL : (Z + (size_t)(R0 + 23) * 512)) + swz_el;
  // panel 0: ig -> gate i rows [0,512)+n0 ; f -> gate f rows 512 + fb*256
  const int RB0 = (isig ? n0 : 512 + fb * 256) + wid * 32 + lr;
  const ushort* pb0 = Wt + (size_t)(RB0)      * 1024 + swz_el;
  const ushort* pb1 = Wt + (size_t)(RB0 + 8)  * 1024 + swz_el;
  const ushort* pb2 = Wt + (size_t)(RB0 + 16) * 1024 + swz_el;
  const ushort* pb3 = Wt + (size_t)(RB0 + 24) * 1024 + swz_el;
  // panel 1: ig -> gate g rows [1024,1536)+n0 ; f -> gate f rows 512+fb*256+128
  const int RB1 = (isig ? 1024 + n0 : 512 + fb * 256 + 128) + wid * 32 + lr;
  const ushort* pq0 = Wt + (size_t)(RB1)      * 1024 + swz_el;
  const ushort* pq1 = Wt + (size_t)(RB1 + 8)  * 1024 + swz_el;
  const ushort* pq2 = Wt + (size_t)(RB1 + 16) * 1024 + swz_el;
  const ushort* pq3 = Wt + (size_t)(RB1 + 24) * 1024 + swz_el;

  const int so0 = fr * 64 + ((fq)     ^ (fr & 7)) * 8;
  const int so1 = fr * 64 + ((4 + fq) ^ (fr & 7)) * 8;

  f32x4 zz = {0.f,0.f,0.f,0.f};
  f32x4 c00=zz,c01=zz,c02=zz,c03=zz, c10=zz,c11=zz,c12=zz,c13=zz,
        c20=zz,c21=zz,c22=zz,c23=zz, c30=zz,c31=zz,c32=zz,c33=zz;
  f32x4 d00=zz,d01=zz,d02=zz,d03=zz, d10=zz,d11=zz,d12=zz,d13=zz,
        d20=zz,d21=zz,d22=zz,d23=zz, d30=zz,d31=zz,d32=zz,d33=zz;

#define STG8(P0,P1,P2,P3, KO, DST) { \
    char* d_ = (char*)(DST) + wid * 4096; \
    gload_lds16((P0) + (KO), d_);        gload_lds16((P1) + (KO), d_ + 1024); \
    gload_lds16((P2) + (KO), d_ + 2048); gload_lds16((P3) + (KO), d_ + 3072); }

#define RDA(SO) \
    const s16x8 fa0 = *(const s16x8*)&As[wr * 4096 + 0 * 1024 + (SO)]; \
    const s16x8 fa1 = *(const s16x8*)&As[wr * 4096 + 1 * 1024 + (SO)]; \
    const s16x8 fa2 = *(const s16x8*)&As[wr * 4096 + 2 * 1024 + (SO)]; \
    const s16x8 fa3 = *(const s16x8*)&As[wr * 4096 + 3 * 1024 + (SO)];

#define RDB(BS, SO) \
    const s16x8 fb0 = *(const s16x8*)&(BS)[wc * 4096 + 0 * 1024 + (SO)]; \
    const s16x8 fb1 = *(const s16x8*)&(BS)[wc * 4096 + 1 * 1024 + (SO)]; \
    const s16x8 fb2 = *(const s16x8*)&(BS)[wc * 4096 + 2 * 1024 + (SO)]; \
    const s16x8 fb3 = *(const s16x8*)&(BS)[wc * 4096 + 3 * 1024 + (SO)];

#define MMC \
    MF(c00,fa0,fb0) MF(c01,fa0,fb1) MF(c02,fa0,fb2) MF(c03,fa0,fb3) \
    MF(c10,fa1,fb0) MF(c11,fa1,fb1) MF(c12,fa1,fb2) MF(c13,fa1,fb3) \
    MF(c20,fa2,fb0) MF(c21,fa2,fb1) MF(c22,fa2,fb2) MF(c23,fa2,fb3) \
    MF(c30,fa3,fb0) MF(c31,fa3,fb1) MF(c32,fa3,fb2) MF(c33,fa3,fb3)

#define MMD \
    MF(d00,fa0,fb0) MF(d01,fa0,fb1) MF(d02,fa0,fb2) MF(d03,fa0,fb3) \
    MF(d10,fa1,fb0) MF(d11,fa1,fb1) MF(d12,fa1,fb2) MF(d13,fa1,fb3) \
    MF(d20,fa2,fb0) MF(d21,fa2,fb1) MF(d22,fa2,fb2) MF(d23,fa2,fb3) \
    MF(d30,fa3,fb0) MF(d31,fa3,fb1) MF(d32,fa3,fb2) MF(d33,fa3,fb3)

#define KSTEP(SO_) { \
    RDA(SO_) \
    { RDB(Bs0, SO_) MMC } \
    { RDB(Bs1, SO_) MMD } }

  // half 1: A = z_t (rows R0), B k-cols [0,512)
  for (int k0 = 0; k0 < 512; k0 += 64) {
    STG8(pa0, pa1, pa2, pa3, k0, As)
    STG8(pb0, pb1, pb2, pb3, k0, Bs0)
    STG8(pq0, pq1, pq2, pq3, k0, Bs1)
    __syncthreads();
    KSTEP(so0)
    KSTEP(so1)
    __syncthreads();
  }
  // half 2: A = z_prev (rows R0-1 / IL), B k-cols [512,1024)
  for (int k0 = 0; k0 < 512; k0 += 64) {
    STG8(ph0, ph1, ph2, ph3, k0, As)
    STG8(pb0, pb1, pb2, pb3, 512 + k0, Bs0)
    STG8(pq0, pq1, pq2, pq3, 512 + k0, Bs1)
    __syncthreads();
    KSTEP(so0)
    KSTEP(so1)
    __syncthreads();
  }
#undef KSTEP
#undef MMD
#undef MMC
#undef RDB
#undef RDA
#undef STG8

  if (isig) {
    // P = sigmoid(i + bi) * tanh(g + bc) -> cols [0,512)
#define EPI(cmn, dmn, m_, n_) { \
    const int col = n0 + wc * 64 + n_ * 16 + fr; \
    const float bvi = biv[col], bvc = bcv[col]; \
    const int rbase = wr * 64 + m_ * 16 + fq * 4; \
    _Pragma("unroll") for (int j = 0; j < 4; ++j) { \
      const float iv = 1.f / (1.f + __expf(-(cmn[j] + bvi))); \
      const float gv = 2.f / (1.f + __expf(-2.f * (dmn[j] + bvc))) - 1.f; \
      G2[(size_t)(r0c + rbase + j) * 1024 + col] = f2h(iv * gv); } }
    EPI(c00, d00, 0, 0) EPI(c01, d01, 0, 1) EPI(c02, d02, 0, 2) EPI(c03, d03, 0, 3)
    EPI(c10, d10, 1, 0) EPI(c11, d11, 1, 1) EPI(c12, d12, 1, 2) EPI(c13, d13, 1, 3)
    EPI(c20, d20, 2, 0) EPI(c21, d21, 2, 1) EPI(c22, d22, 2, 2) EPI(c23, d23, 2, 3)
    EPI(c30, d30, 3, 0) EPI(c31, d31, 3, 1) EPI(c32, d32, 3, 2) EPI(c33, d33, 3, 3)
#undef EPI
  } else {
    // F = sigmoid(f + bf): c accs -> cols fb*256+[0,128); d accs -> +128
#define EPIF(cmn, m_, n_, COFF) { \
    const int col = fb * 256 + (COFF) + wc * 64 + n_ * 16 + fr; \
    const float bv = bfv[col]; \
    const int rbase = wr * 64 + m_ * 16 + fq * 4; \
    _Pragma("unroll") for (int j = 0; j < 4; ++j) { \
      const float fv = 1.f / (1.f + __expf(-(cmn[j] + bv))); \
      G2[(size_t)(r0c + rbase + j) * 1024 + 512 + col] = f2h(fv); } }
    EPIF(c00, 0, 0, 0) EPIF(c01, 0, 1, 0) EPIF(c02, 0, 2, 0) EPIF(c03, 0, 3, 0)
    EPIF(c10, 1, 0, 0) EPIF(c11, 1, 1, 0) EPIF(c12, 1, 2, 0) EPIF(c13, 1, 3, 0)
    EPIF(c20, 2, 0, 0) EPIF(c21, 2, 1, 0) EPIF(c22, 2, 2, 0) EPIF(c23, 2, 3, 0)
    EPIF(c30, 3, 0, 0) EPIF(c31, 3, 1, 0) EPIF(c32, 3, 2, 0) EPIF(c33, 3, 3, 0)
    EPIF(d00, 0, 0, 128) EPIF(d01, 0, 1, 128) EPIF(d02, 0, 2, 128) EPIF(d03, 0, 3, 128)
    EPIF(d10, 1, 0, 128) EPIF(d11, 1, 1, 128) EPIF(d12, 1, 2, 128) EPIF(d13, 1, 3, 128)
    EPIF(d20, 2, 0, 128) EPIF(d21, 2, 1, 128) EPIF(d22, 2, 2, 128) EPIF(d23, 2, 3, 128)
    EPIF(d30, 3, 0, 128) EPIF(d31, 3, 1, 128) EPIF(d32, 3, 2, 128) EPIF(d33, 3, 3, 128)
#undef EPIF
  }
}

// ------------------------------------------------ scan phase A
__global__ __launch_bounds__(256) void k3a_seg(
    const ushort* __restrict__ G2, float* __restrict__ Aseg,
    float* __restrict__ Bseg, int Tc)
{
  const int l = blockIdx.x * 256 + threadIdx.x;
  const int b = blockIdx.y, s = blockIdx.z;
  const int SEGc = Tc >> 6;
  const ushort* gb = G2 + ((size_t)(b * Tc + s * 64)) * 1024 + l;
  float A = 1.f, c = 0.f;
#pragma unroll 8
  for (int j = 0; j < 64; ++j) {
    const float P = h2f(gb[(size_t)j * 1024]);
    const float F = h2f(gb[(size_t)j * 1024 + 512]);
    A *= F;
    c = fmaf(F, c, P);
  }
  const size_t o = (size_t)(b * SEGc + s) * 512 + l;
  Aseg[o] = A;
  Bseg[o] = c;
}

// ------------------------------------------------ scan phase B
__global__ __launch_bounds__(512) void k3b_comb(
    const float* __restrict__ Aseg, const float* __restrict__ Bseg,
    const float* __restrict__ initc, float* __restrict__ cstart,
    float* __restrict__ cbuf, int tc, int Tc)
{
  const int b = blockIdx.x, l = threadIdx.x;
  const int SEGc = Tc >> 6;
  float c = (tc == 0) ? initc[l] : cbuf[b * 512 + l];
  for (int s = 0; s < SEGc; ++s) {
    const size_t o = (size_t)(b * SEGc + s) * 512 + l;
    cstart[o] = c;
    c = fmaf(Aseg[o], c, Bseg[o]);
  }
  cbuf[b * 512 + l] = c;
}

// ------------------------------------------------ scan phase C
__global__ __launch_bounds__(128) void k3c_emit(
    const ushort* __restrict__ G2, const ushort* __restrict__ Z,
    const float* __restrict__ cstart, float* __restrict__ out,
    int tc, int Tc)
{
  __shared__ float tile[128][65];
  const int tid = threadIdx.x;
  const int l0 = blockIdx.x * 128;
  const int b = blockIdx.y, s = blockIdx.z;
  const int SEGc = Tc >> 6;
  const int l = l0 + tid;

  float c = cstart[(size_t)(b * SEGc + s) * 512 + l];
  const ushort* gb = G2 + ((size_t)(b * Tc + s * 64)) * 1024 + l;
  const ushort* zb = Z + ((size_t)(b * 1024 + tc + s * 64)) * 512 + l;
#pragma unroll 8
  for (int j = 0; j < 64; ++j) {
    const float P = h2f(gb[(size_t)j * 1024]);
    const float F = h2f(gb[(size_t)j * 1024 + 512]);
    const float zv = bf2f(zb[(size_t)j * 512]);
    c = fmaf(F, c, P);
    tile[tid][j] = sinf(zv) * c;
  }
  __syncthreads();
  const int col = tid & 63, rhalf = tid >> 6;
  const size_t obase = ((size_t)b * 512 + l0) * 1024 + (size_t)(tc + s * 64) + col;
#pragma unroll
  for (int p = 0; p < 64; ++p) {
    const int row = rhalf + p * 2;
    out[obase + (size_t)row * 1024] = tile[row][col];
  }
}

// ------------------------------------------------ launcher
extern "C" void kernel_launch(void* const* d_in, const int* in_sizes, int n_in,
                              void* d_out, int out_size, void* d_ws, size_t ws_size,
                              hipStream_t stream)
{
  const float* x  = (const float*)d_in[0];
  const float* W  = (const float*)d_in[1];
  const float* rb = (const float*)d_in[2];
  const float* wi = (const float*)d_in[3];
  const float* wf = (const float*)d_in[4];
  const float* wc = (const float*)d_in[5];
  const float* ri = (const float*)d_in[6];
  const float* rf = (const float*)d_in[7];
  const float* rc = (const float*)d_in[8];
  const float* bi = (const float*)d_in[9];
  const float* bfo = (const float*)d_in[10];
  const float* bc = (const float*)d_in[11];
  const float* il = (const float*)d_in[12];
  const float* ic = (const float*)d_in[13];
  float* out = (float*)d_out;

  char* ws = (char*)d_ws;
  size_t off = 0;
  auto alloc = [&](size_t bytes) -> void* {
    void* p = ws + off;
    off = (off + bytes + 255) & ~(size_t)255;
    return p;
  };
  ushort* z    = (ushort*)alloc((size_t)65536 * 512 * 2);   // 67.1 MB
  ushort* W1t  = (ushort*)alloc((size_t)512 * 512 * 2);
  ushort* W2t  = (ushort*)alloc((size_t)1536 * 1024 * 2);
  ushort* ilb  = (ushort*)alloc(512 * 2);
  float*  cbuf = (float*)alloc((size_t)64 * 512 * 4);
  float*  Aseg = (float*)alloc((size_t)64 * 16 * 512 * 4);  // 2 MB
  float*  Bseg = (float*)alloc((size_t)64 * 16 * 512 * 4);
  float*  cstart = (float*)alloc((size_t)64 * 16 * 512 * 4);
  const size_t fixed_end = off;
  ushort* xt   = (ushort*)alloc((size_t)65536 * 512 * 2);   // dead after K1
  ushort* G2   = (ushort*)(ws + fixed_end);                 // aliases xt region
  ushort* u    = (ushort*)d_out;                            // dead before k3c

  int Tc = 1024;
  while (Tc > 128 && fixed_end + (size_t)64 * Tc * 1024 * 2 > ws_size) Tc >>= 1;

  // prep
  transpose8<<<dim3(16, 16, 8), 256, 0, stream>>>(
      wi, ri, wf, rf, wc, rc, il, W, W2t, ilb, W1t);
  transpose_x<<<dim3(16, 8, 64), 256, 0, stream>>>(x, xt);

  k1_mfma<<<dim3(2048), 256, 0, stream>>>(xt, W1t, rb, u);
  ln_rows<<<16384, 256, 0, stream>>>(u, z);

  for (int tc = 0; tc < 1024; tc += Tc) {
    const int SEGc = Tc >> 6;
    const int nwg2 = 6 * 64 * (Tc >> 7);
    k2_mfma<<<dim3(nwg2), 256, 0, stream>>>(
        z, W2t, ilb, bi, bfo, bc, G2, tc, Tc, nwg2);
    k3a_seg<<<dim3(2, 64, SEGc), 256, 0, stream>>>(G2, Aseg, Bseg, Tc);
    k3b_comb<<<64, 512, 0, stream>>>(Aseg, Bseg, ic, cstart, cbuf, tc, Tc);
    k3c_emit<<<dim3(4, 64, SEGc), 128, 0, stream>>>(G2, z, cstart, out, tc, Tc);
  }
}